// Round 3
// baseline (584.279 us; speedup 1.0000x reference)
//
#include <hip/hip_runtime.h>
#include <hip/hip_cooperative_groups.h>
#include <math.h>

namespace cg = cooperative_groups;

#define B_    32
#define H_    512
#define W_    512
#define NBINS 256
#define NT    254
#define HW_   (H_ * W_)

// ws layout:
//   [0      .. 32768)  int   hist[32][256]
//   [32768  .. 33024)  ull   packed[32]
//   [33024  .. 33152)  float sq[32]
//   [33152  .. 33280)  float sm[32]
//   [33280  .. 33284)  int   counter
// all zeroed in-kernel (coop path) or via memset (fallback path)
#define NZERO_INTS 8324   // 33296 bytes / 4

__device__ __forceinline__ float max5(float a, float b, float c, float d, float e) {
    return fmaxf(fmaxf(fmaxf(a, b), fmaxf(c, d)), e);
}

__device__ __forceinline__ int bin_of(float im) {
    float v = im * 255.0f;                  // reference: v = imgs*255
    float u = v * (256.0f / 255.0f);        // reference: v*(NBINS/255.0) in f32
    int bin = (int)floorf(u);
    return bin < 0 ? 0 : (bin > NBINS - 1 ? NBINS - 1 : bin);
}

// ===========================================================================
// Fused cooperative kernel: zero-ws + dilate/hist + search + loss + final.
// 1024 blocks x 256 thr = 4 blocks/CU resident (launch_bounds caps VGPR@128).
// Wave = full 512-col row span; lane = 8 cols; horizontal max via shuffles
// (no LDS tile -> no bank conflicts, no staging barriers).
// ===========================================================================
__global__ __launch_bounds__(256, 4) void k_fused(
    const float* __restrict__ preds, const float* __restrict__ labels,
    const float* __restrict__ images,
    int* __restrict__ hist, unsigned long long* __restrict__ packed,
    float* __restrict__ sq, float* __restrict__ sm,
    int* __restrict__ counter, float* __restrict__ out,
    int* __restrict__ wszero, int nzero)
{
    __shared__ int   s_hist[NBINS];
    __shared__ float sA[NBINS];
    __shared__ float sB[NBINS];
    __shared__ float sPQ[NBINS][2];
    __shared__ float sT0[32];
    __shared__ float sT2[NBINS];
    __shared__ int   s_int[256];
    __shared__ unsigned long long s_pack[256];
    __shared__ float s_red[256];
    __shared__ int   s_ticket;

    cg::grid_group grid = cg::this_grid();

    const int tid   = threadIdx.x;
    const int lane  = tid & 63;
    const int w     = tid >> 6;             // wave 0..3
    const int b     = blockIdx.x >> 5;      // batch
    const int band  = blockIdx.x & 31;      // 16-row band
    const int rbase = band * 16 + w * 4;    // this wave's 4 output rows
    const int c0    = lane * 8;             // this lane's 8 cols
    const float* lab = labels + (size_t)b * HW_;
    const float* img = images + (size_t)b * HW_;

    // ---- zero ws accumulators (grid-strided; visible after grid.sync #1) ----
    {
        int gid = blockIdx.x * 256 + tid;
        if (gid < nzero) wszero[gid] = 0;
    }
    s_hist[tid] = 0;
    __syncthreads();

    // ---- phase 1: vertical 5-max in regs, horizontal 5-max via shuffles ----
    float win[8][8];                        // label rows rbase-2 .. rbase+5
#pragma unroll
    for (int k = 0; k < 8; ++k) {
        int gr = rbase - 2 + k;
        if ((unsigned)gr < (unsigned)H_) {
            float4 a  = *(const float4*)(lab + gr * W_ + c0);
            float4 bq = *(const float4*)(lab + gr * W_ + c0 + 4);
            win[k][0] = a.x;  win[k][1] = a.y;  win[k][2] = a.z;  win[k][3] = a.w;
            win[k][4] = bq.x; win[k][5] = bq.y; win[k][6] = bq.z; win[k][7] = bq.w;
        } else {
#pragma unroll
            for (int c = 0; c < 8; ++c) win[k][c] = 0.0f;
        }
    }

    unsigned mask = 0;                      // 4 rows x 8 cols dilated-mask bits
#pragma unroll
    for (int r = 0; r < 4; ++r) {
        float vm[8];
#pragma unroll
        for (int c = 0; c < 8; ++c)
            vm[c] = max5(win[r][c], win[r+1][c], win[r+2][c], win[r+3][c], win[r+4][c]);
        float l2 = __shfl_up(vm[6], 1);     // col c0-2 (neighbor's col 6)
        float l1 = __shfl_up(vm[7], 1);     // col c0-1
        float r1 = __shfl_down(vm[0], 1);   // col c0+8
        float r2 = __shfl_down(vm[1], 1);   // col c0+9
        if (lane == 0)  { l1 = 0.0f; l2 = 0.0f; }   // image edge zero-pad
        if (lane == 63) { r1 = 0.0f; r2 = 0.0f; }
        float e[12];
        e[0] = l2; e[1] = l1;
#pragma unroll
        for (int c = 0; c < 8; ++c) e[c + 2] = vm[c];
        e[10] = r1; e[11] = r2;
        unsigned mrow = 0;
#pragma unroll
        for (int c = 0; c < 8; ++c) {
            float hm = max5(e[c], e[c+1], e[c+2], e[c+3], e[c+4]);
            if (hm > 0.0f) mrow |= (1u << c);
        }
        if (mrow & 0xFu) {
            float4 iv = *(const float4*)(img + (rbase + r) * W_ + c0);
            if (mrow & 1u) atomicAdd(&s_hist[bin_of(iv.x)], 1);
            if (mrow & 2u) atomicAdd(&s_hist[bin_of(iv.y)], 1);
            if (mrow & 4u) atomicAdd(&s_hist[bin_of(iv.z)], 1);
            if (mrow & 8u) atomicAdd(&s_hist[bin_of(iv.w)], 1);
        }
        if (mrow >> 4) {
            float4 iv = *(const float4*)(img + (rbase + r) * W_ + c0 + 4);
            if (mrow & 16u)  atomicAdd(&s_hist[bin_of(iv.x)], 1);
            if (mrow & 32u)  atomicAdd(&s_hist[bin_of(iv.y)], 1);
            if (mrow & 64u)  atomicAdd(&s_hist[bin_of(iv.z)], 1);
            if (mrow & 128u) atomicAdd(&s_hist[bin_of(iv.w)], 1);
        }
        mask |= mrow << (r * 8);
    }
    __syncthreads();
    grid.sync();                            // #1: ws zeroing complete

    {   // flush block-local histogram
        int c = s_hist[tid];
        if (c) atomicAdd(&hist[b * NBINS + tid], c);
    }
    __threadfence();
    grid.sync();                            // #2: global hist complete

    // ---- phase 2: Otsu search (8 slices x 32 batches on blocks 0..255) ----
    if (blockIdx.x < 256) {
        const int slice = blockIdx.x & 7;
        const int b2    = blockIdx.x >> 3;
        const float s   = 1e-8f;

        int h = __hip_atomic_load(&hist[b2 * NBINS + tid],
                                  __ATOMIC_RELAXED, __HIP_MEMORY_SCOPE_AGENT);
        s_int[tid] = h;
        __syncthreads();
        for (int off = 128; off > 0; off >>= 1) {   // exact: integer counts
            if (tid < off) s_int[tid] += s_int[tid + off];
            __syncthreads();
        }
        const float ftot = (float)s_int[0];
        __syncthreads();

        float p = (float)h / ftot;
        sPQ[tid][0] = p;
        sPQ[tid][1] = p * (float)tid;
        __syncthreads();

        if (tid == 0) {                     // sequential fold == reference cumsum
            float ch = 0.0f, cm = 0.0f;
#pragma unroll 8
            for (int i = 0; i < NBINS; ++i) {
                ch += sPQ[i][0];
                cm += sPQ[i][1];
                sA[i] = ch;
                sB[i] = cm;
            }
        }
        __syncthreads();

        const float tm = sB[NBINS - 1];
        if (tid < NT) {
            float cb = sA[tid];
            float w2 = 1.0f - cb;
            float mean2 = (tm - sB[tid]) / (w2 + s);
            float d2 = mean2 - tm;
            sT2[tid] = w2 * (d2 * d2);
        }
        const int i0 = slice * 32;
        if (tid < 32) {
            int i = i0 + tid;
            if (i < NT) {
                float w0 = sA[i];
                float mean0 = sB[i] / (w0 + s);
                float d0 = mean0 - tm;
                sT0[tid] = w0 * (d0 * d0);
            }
        }
        __syncthreads();

        unsigned long long best = 0ull;
        if (tid < NT) {
            const float cb  = sA[tid];
            const float m1v = sB[tid];
            const float w2  = 1.0f - cb;
            const float t2v = sT2[tid];
#pragma unroll 4
            for (int il = 0; il < 32; ++il) {
                int i = i0 + il;
                if (i >= NT) break;
                float w0 = sA[i];
                float w1 = cb - w0;
                float mean1 = (m1v - sB[i]) / (w1 + s);
                float d1 = mean1 - tm;
                float bv = (sT0[il] + w1 * (d1 * d1)) + t2v;
                bool ok = (w0 > 0.f) && (w1 > 0.f) && (w2 > 0.f);
                bv = ok ? bv : 0.0f;
                unsigned k = (unsigned)(i * NT + tid);
                unsigned long long pk =
                    ((unsigned long long)__float_as_uint(bv) << 32) | (0xFFFFFFFFu - k);
                best = pk > best ? pk : best;
            }
        }
        s_pack[tid] = best;
        __syncthreads();
        for (int off = 128; off > 0; off >>= 1) {
            if (tid < off) {
                unsigned long long o = s_pack[tid + off];
                if (o > s_pack[tid]) s_pack[tid] = o;
            }
            __syncthreads();
        }
        if (tid == 0) {
            atomicMax(&packed[b2], s_pack[0]);
            if (slice == 0) sm[b2] = ftot;
        }
    }
    __threadfence();
    grid.sync();                            // #3: packed + sm complete

    // ---- phase 3: loss using register-held mask ----
    unsigned long long pk = __hip_atomic_load(&packed[b],
                                 __ATOMIC_RELAXED, __HIP_MEMORY_SCOPE_AGENT);
    unsigned am = 0xFFFFFFFFu - (unsigned)(pk & 0xFFFFFFFFull);
    int ti = (int)(am / NT);
    int tj = (int)(am % NT);
    const float t1 = (float)(ti + 1) / 255.0f;
    const float t2 = (float)(tj + 1) / 255.0f;
    const float* prd = preds + (size_t)b * HW_;

    float acc = 0.0f;
#pragma unroll
    for (int r = 0; r < 4; ++r) {
        unsigned mrow = (mask >> (r * 8)) & 0xFFu;
        size_t off = (size_t)(rbase + r) * W_ + c0;
        if (mrow & 0xFu) {
            float4 iv = *(const float4*)(img + off);
            float4 pv = *(const float4*)(prd + off);
            if (mrow & 1u) { float ci = iv.x >= t2 ? 1.f : (iv.x >= t1 ? 0.5f : 0.f); float d = ci - pv.x; acc += d * d; }
            if (mrow & 2u) { float ci = iv.y >= t2 ? 1.f : (iv.y >= t1 ? 0.5f : 0.f); float d = ci - pv.y; acc += d * d; }
            if (mrow & 4u) { float ci = iv.z >= t2 ? 1.f : (iv.z >= t1 ? 0.5f : 0.f); float d = ci - pv.z; acc += d * d; }
            if (mrow & 8u) { float ci = iv.w >= t2 ? 1.f : (iv.w >= t1 ? 0.5f : 0.f); float d = ci - pv.w; acc += d * d; }
        }
        if (mrow >> 4) {
            float4 iv = *(const float4*)(img + off + 4);
            float4 pv = *(const float4*)(prd + off + 4);
            if (mrow & 16u)  { float ci = iv.x >= t2 ? 1.f : (iv.x >= t1 ? 0.5f : 0.f); float d = ci - pv.x; acc += d * d; }
            if (mrow & 32u)  { float ci = iv.y >= t2 ? 1.f : (iv.y >= t1 ? 0.5f : 0.f); float d = ci - pv.y; acc += d * d; }
            if (mrow & 64u)  { float ci = iv.z >= t2 ? 1.f : (iv.z >= t1 ? 0.5f : 0.f); float d = ci - pv.z; acc += d * d; }
            if (mrow & 128u) { float ci = iv.w >= t2 ? 1.f : (iv.w >= t1 ? 0.5f : 0.f); float d = ci - pv.w; acc += d * d; }
        }
    }
    s_red[tid] = acc;
    __syncthreads();
    for (int off = 128; off > 0; off >>= 1) {
        if (tid < off) s_red[tid] += s_red[tid + off];
        __syncthreads();
    }
    if (tid == 0) {
        atomicAdd(&sq[b], s_red[0]);
        __threadfence();
        s_ticket = atomicAdd(counter, 1);
    }
    __syncthreads();

    if (s_ticket == (int)gridDim.x - 1) {   // last block: valid-batch mean
        if (tid < 64) {
            float lp = 0.0f, vc = 0.0f;
            if (tid < B_) {
                float sqv = atomicAdd(&sq[tid], 0.0f);
                float smv = __hip_atomic_load(&sm[tid], __ATOMIC_RELAXED,
                                              __HIP_MEMORY_SCOPE_AGENT) + 1e-8f;
                if (smv > 1e-8f) { lp = sqv / smv; vc = 1.0f; }
            }
            for (int o = 32; o > 0; o >>= 1) {
                lp += __shfl_down(lp, o);
                vc += __shfl_down(vc, o);
            }
            if (tid == 0) out[0] = vc > 0.0f ? lp / fmaxf(vc, 1.0f) : 0.0f;
        }
    }
}

// ===========================================================================
// Fallback path (R2 kernels, verbatim semantics) — used only if cooperative
// launch is rejected (e.g. by graph capture).
// ===========================================================================
__global__ __launch_bounds__(256) void k_hist_fb(const float* __restrict__ labels,
                                                 const float* __restrict__ images,
                                                 int* __restrict__ hist) {
    __shared__ float s_v[16][520];
    __shared__ int   s_hist[NBINS];
    const int tid   = threadIdx.x;
    const int band  = blockIdx.x;
    const int b     = blockIdx.y;
    const int strip = tid & 127;
    const int half  = tid >> 7;
    const int c0    = strip * 4;
    const int rbase = band * 16 + half * 8;
    const float* lab = labels + (size_t)b * HW_;
    const float* img = images + (size_t)b * HW_;
    s_hist[tid] = 0;
    if (tid < 128) { int r = tid >> 3, cc = tid & 7; s_v[r][cc < 4 ? cc : 512 + cc] = 0.0f; }
    float4 l[12];
#pragma unroll
    for (int k = 0; k < 12; ++k) {
        int gr = rbase - 2 + k;
        l[k] = ((unsigned)gr < (unsigned)H_) ? *(const float4*)(lab + (size_t)gr * W_ + c0)
                                             : make_float4(0.f, 0.f, 0.f, 0.f);
    }
#pragma unroll
    for (int r = 0; r < 8; ++r) {
        float4 m;
        m.x = max5(l[r].x, l[r+1].x, l[r+2].x, l[r+3].x, l[r+4].x);
        m.y = max5(l[r].y, l[r+1].y, l[r+2].y, l[r+3].y, l[r+4].y);
        m.z = max5(l[r].z, l[r+1].z, l[r+2].z, l[r+3].z, l[r+4].z);
        m.w = max5(l[r].w, l[r+1].w, l[r+2].w, l[r+3].w, l[r+4].w);
        *(float4*)&s_v[half * 8 + r][c0 + 4] = m;
    }
    __syncthreads();
#pragma unroll
    for (int r = 0; r < 8; ++r) {
        const float* f = &s_v[half * 8 + r][c0 + 2];
        float h0 = max5(f[0], f[1], f[2], f[3], f[4]);
        float h1 = max5(f[1], f[2], f[3], f[4], f[5]);
        float h2 = max5(f[2], f[3], f[4], f[5], f[6]);
        float h3 = max5(f[3], f[4], f[5], f[6], f[7]);
        if (h0 > 0.f || h1 > 0.f || h2 > 0.f || h3 > 0.f) {
            float4 iv = *(const float4*)(img + (size_t)(rbase + r) * W_ + c0);
            if (h0 > 0.f) atomicAdd(&s_hist[bin_of(iv.x)], 1);
            if (h1 > 0.f) atomicAdd(&s_hist[bin_of(iv.y)], 1);
            if (h2 > 0.f) atomicAdd(&s_hist[bin_of(iv.z)], 1);
            if (h3 > 0.f) atomicAdd(&s_hist[bin_of(iv.w)], 1);
        }
    }
    __syncthreads();
    int c = s_hist[tid];
    if (c) atomicAdd(&hist[b * NBINS + tid], c);
}

__global__ __launch_bounds__(256) void k_search_fb(const int* __restrict__ hist,
                                                   unsigned long long* __restrict__ packed,
                                                   float* __restrict__ sm) {
    __shared__ float sA[NBINS];
    __shared__ float sB[NBINS];
    __shared__ float sPQ[NBINS][2];
    __shared__ float sT0[32];
    __shared__ float sT2[NBINS];
    __shared__ int   s_int[256];
    __shared__ unsigned long long s_pack[256];
    const int tid   = threadIdx.x;
    const int slice = blockIdx.x;
    const int b     = blockIdx.y;
    const float s   = 1e-8f;
    int h = hist[b * NBINS + tid];
    s_int[tid] = h;
    __syncthreads();
    for (int off = 128; off > 0; off >>= 1) {
        if (tid < off) s_int[tid] += s_int[tid + off];
        __syncthreads();
    }
    const float ftot = (float)s_int[0];
    __syncthreads();
    float p = (float)h / ftot;
    sPQ[tid][0] = p; sPQ[tid][1] = p * (float)tid;
    __syncthreads();
    if (tid == 0) {
        float ch = 0.0f, cm = 0.0f;
#pragma unroll 8
        for (int i = 0; i < NBINS; ++i) { ch += sPQ[i][0]; cm += sPQ[i][1]; sA[i] = ch; sB[i] = cm; }
    }
    __syncthreads();
    const float tm = sB[NBINS - 1];
    if (tid < NT) {
        float cb = sA[tid]; float w2 = 1.0f - cb;
        float mean2 = (tm - sB[tid]) / (w2 + s); float d2 = mean2 - tm;
        sT2[tid] = w2 * (d2 * d2);
    }
    const int i0 = slice * 32;
    if (tid < 32) {
        int i = i0 + tid;
        if (i < NT) {
            float w0 = sA[i]; float mean0 = sB[i] / (w0 + s); float d0 = mean0 - tm;
            sT0[tid] = w0 * (d0 * d0);
        }
    }
    __syncthreads();
    unsigned long long best = 0ull;
    if (tid < NT) {
        const float cb = sA[tid], m1v = sB[tid];
        const float w2 = 1.0f - cb, t2v = sT2[tid];
#pragma unroll 4
        for (int il = 0; il < 32; ++il) {
            int i = i0 + il;
            if (i >= NT) break;
            float w0 = sA[i]; float w1 = cb - w0;
            float mean1 = (m1v - sB[i]) / (w1 + s); float d1 = mean1 - tm;
            float bv = (sT0[il] + w1 * (d1 * d1)) + t2v;
            bool ok = (w0 > 0.f) && (w1 > 0.f) && (w2 > 0.f);
            bv = ok ? bv : 0.0f;
            unsigned k = (unsigned)(i * NT + tid);
            unsigned long long pk =
                ((unsigned long long)__float_as_uint(bv) << 32) | (0xFFFFFFFFu - k);
            best = pk > best ? pk : best;
        }
    }
    s_pack[tid] = best;
    __syncthreads();
    for (int off = 128; off > 0; off >>= 1) {
        if (tid < off) { unsigned long long o = s_pack[tid + off]; if (o > s_pack[tid]) s_pack[tid] = o; }
        __syncthreads();
    }
    if (tid == 0) {
        atomicMax(&packed[b], s_pack[0]);
        if (slice == 0) sm[b] = ftot;
    }
}

__global__ __launch_bounds__(256) void k_loss_fb(const float* __restrict__ labels,
                                                 const float* __restrict__ images,
                                                 const float* __restrict__ preds,
                                                 const unsigned long long* __restrict__ packed,
                                                 float* __restrict__ sq,
                                                 const float* __restrict__ sm,
                                                 int* __restrict__ counter,
                                                 float* __restrict__ out) {
    __shared__ float s_v[16][520];
    __shared__ float s_red[256];
    __shared__ int   s_ticket;
    const int tid   = threadIdx.x;
    const int band  = blockIdx.x;
    const int b     = blockIdx.y;
    const int strip = tid & 127;
    const int half  = tid >> 7;
    const int c0    = strip * 4;
    const int rbase = band * 16 + half * 8;
    const float* lab = labels + (size_t)b * HW_;
    const float* img = images + (size_t)b * HW_;
    const float* prd = preds  + (size_t)b * HW_;
    unsigned long long pk = packed[b];
    unsigned am = 0xFFFFFFFFu - (unsigned)(pk & 0xFFFFFFFFull);
    const float t1 = (float)((int)(am / NT) + 1) / 255.0f;
    const float t2 = (float)((int)(am % NT) + 1) / 255.0f;
    if (tid < 128) { int r = tid >> 3, cc = tid & 7; s_v[r][cc < 4 ? cc : 512 + cc] = 0.0f; }
    float4 l[12];
#pragma unroll
    for (int k = 0; k < 12; ++k) {
        int gr = rbase - 2 + k;
        l[k] = ((unsigned)gr < (unsigned)H_) ? *(const float4*)(lab + (size_t)gr * W_ + c0)
                                             : make_float4(0.f, 0.f, 0.f, 0.f);
    }
#pragma unroll
    for (int r = 0; r < 8; ++r) {
        float4 m;
        m.x = max5(l[r].x, l[r+1].x, l[r+2].x, l[r+3].x, l[r+4].x);
        m.y = max5(l[r].y, l[r+1].y, l[r+2].y, l[r+3].y, l[r+4].y);
        m.z = max5(l[r].z, l[r+1].z, l[r+2].z, l[r+3].z, l[r+4].z);
        m.w = max5(l[r].w, l[r+1].w, l[r+2].w, l[r+3].w, l[r+4].w);
        *(float4*)&s_v[half * 8 + r][c0 + 4] = m;
    }
    __syncthreads();
    float acc = 0.0f;
#pragma unroll
    for (int r = 0; r < 8; ++r) {
        const float* f = &s_v[half * 8 + r][c0 + 2];
        float h0 = max5(f[0], f[1], f[2], f[3], f[4]);
        float h1 = max5(f[1], f[2], f[3], f[4], f[5]);
        float h2 = max5(f[2], f[3], f[4], f[5], f[6]);
        float h3 = max5(f[3], f[4], f[5], f[6], f[7]);
        if (h0 > 0.f || h1 > 0.f || h2 > 0.f || h3 > 0.f) {
            size_t off = (size_t)(rbase + r) * W_ + c0;
            float4 iv = *(const float4*)(img + off);
            float4 pv = *(const float4*)(prd + off);
            if (h0 > 0.f) { float ci = iv.x >= t2 ? 1.f : (iv.x >= t1 ? 0.5f : 0.f); float d = ci - pv.x; acc += d * d; }
            if (h1 > 0.f) { float ci = iv.y >= t2 ? 1.f : (iv.y >= t1 ? 0.5f : 0.f); float d = ci - pv.y; acc += d * d; }
            if (h2 > 0.f) { float ci = iv.z >= t2 ? 1.f : (iv.z >= t1 ? 0.5f : 0.f); float d = ci - pv.z; acc += d * d; }
            if (h3 > 0.f) { float ci = iv.w >= t2 ? 1.f : (iv.w >= t1 ? 0.5f : 0.f); float d = ci - pv.w; acc += d * d; }
        }
    }
    s_red[tid] = acc;
    __syncthreads();
    for (int off = 128; off > 0; off >>= 1) {
        if (tid < off) s_red[tid] += s_red[tid + off];
        __syncthreads();
    }
    if (tid == 0) {
        atomicAdd(&sq[b], s_red[0]);
        __threadfence();
        s_ticket = atomicAdd(counter, 1);
    }
    __syncthreads();
    if (s_ticket == B_ * 32 - 1) {
        if (tid < 64) {
            float lp = 0.0f, vc = 0.0f;
            if (tid < B_) {
                float sqv = atomicAdd(&sq[tid], 0.0f);
                float smv = sm[tid] + 1e-8f;
                if (smv > 1e-8f) { lp = sqv / smv; vc = 1.0f; }
            }
            for (int o = 32; o > 0; o >>= 1) { lp += __shfl_down(lp, o); vc += __shfl_down(vc, o); }
            if (tid == 0) out[0] = vc > 0.0f ? lp / fmaxf(vc, 1.0f) : 0.0f;
        }
    }
}

extern "C" void kernel_launch(void* const* d_in, const int* in_sizes, int n_in,
                              void* d_out, int out_size, void* d_ws, size_t ws_size,
                              hipStream_t stream) {
    const float* preds  = (const float*)d_in[0];
    const float* labels = (const float*)d_in[1];
    const float* images = (const float*)d_in[2];
    float* out = (float*)d_out;

    char* ws = (char*)d_ws;
    int*                hist    = (int*)ws;
    unsigned long long* packed  = (unsigned long long*)(ws + 32768);
    float*              sq      = (float*)(ws + 33024);
    float*              sm      = (float*)(ws + 33152);
    int*                counter = (int*)(ws + 33280);
    int*                wszero  = (int*)ws;
    int                 nzero   = NZERO_INTS;

    void* args[] = { (void*)&preds, (void*)&labels, (void*)&images,
                     (void*)&hist, (void*)&packed, (void*)&sq, (void*)&sm,
                     (void*)&counter, (void*)&out, (void*)&wszero, (void*)&nzero };
    hipError_t err = hipLaunchCooperativeKernel((const void*)k_fused,
                                                dim3(1024), dim3(256),
                                                args, 0, stream);
    if (err != hipSuccess) {
        // fallback: R2 3-kernel path
        hipMemsetAsync(ws, 0, 33296, stream);
        dim3 gdil(32, B_);
        k_hist_fb<<<gdil, 256, 0, stream>>>(labels, images, hist);
        k_search_fb<<<dim3(8, B_), 256, 0, stream>>>(hist, packed, sm);
        k_loss_fb<<<gdil, 256, 0, stream>>>(labels, images, preds, packed, sq, sm,
                                            counter, out);
    }
}

// Round 4
// 185.450 us; speedup vs baseline: 3.1506x; 3.1506x over previous
//
#include <hip/hip_runtime.h>
#include <math.h>

#define B_    32
#define H_    512
#define W_    512
#define NBINS 256
#define NT    254
#define HW_   (H_ * W_)

// ws layout:
//   [0      .. 32768)   int   hist[32][256]     (memset 0)
//   [32768  .. 33024)   ull   packed[32]        (memset 0)
//   [33024  .. 33152)   float sq[32]            (memset 0)
//   [33152  .. 33280)   float sm[32]            (written by k_search)
//   [33280  .. 33284)   int   counter           (memset 0)
//   [33792  .. 1082368) uint  maskbuf[32][512][16]  (all-slots-written, no zeroing)
#define MASK_OFF   33792
#define WS_NEEDED  1082368

__device__ __forceinline__ float max5(float a, float b, float c, float d, float e) {
    return fmaxf(fmaxf(fmaxf(a, b), fmaxf(c, d)), e);
}
__device__ __forceinline__ float4 fmax4(float4 a, float4 b) {
    return make_float4(fmaxf(a.x, b.x), fmaxf(a.y, b.y),
                       fmaxf(a.z, b.z), fmaxf(a.w, b.w));
}
__device__ __forceinline__ int bin_of(float im) {
    float v = im * 255.0f;                  // reference: v = imgs*255
    float u = v * (256.0f / 255.0f);        // reference: v*(NBINS/255.0) in f32
    int bin = (int)floorf(u);
    return bin < 0 ? 0 : (bin > NBINS - 1 ? NBINS - 1 : bin);
}

// Dilated-mask bits (5x5 max > 0) for 2 rows x 8 cols owned by (rbase, c0).
// Vertical 5-max via running float4 accumulators; horizontal via shuffles.
__device__ __forceinline__ void dilate2(const float* __restrict__ lab,
                                        int rbase, int c0, int lane,
                                        unsigned mrow[2]) {
    float4 A0 = make_float4(0.f, 0.f, 0.f, 0.f), B0 = A0, A1 = A0, B1 = A0;
#pragma unroll
    for (int k = 0; k < 6; ++k) {
        int gr = rbase - 2 + k;
        float4 la = make_float4(0.f, 0.f, 0.f, 0.f), lb = la;
        if ((unsigned)gr < (unsigned)H_) {
            la = *(const float4*)(lab + gr * W_ + c0);
            lb = *(const float4*)(lab + gr * W_ + c0 + 4);
        }
        if (k < 5) { A0 = fmax4(A0, la); B0 = fmax4(B0, lb); }
        if (k > 0) { A1 = fmax4(A1, la); B1 = fmax4(B1, lb); }
    }
#pragma unroll
    for (int r = 0; r < 2; ++r) {
        float4 A  = r ? A1 : A0;
        float4 Bq = r ? B1 : B0;
        float l2 = __shfl_up(Bq.z, 1);      // col c0-2 (prev lane col 6)
        float l1 = __shfl_up(Bq.w, 1);      // col c0-1
        float r1 = __shfl_down(A.x, 1);     // col c0+8
        float r2 = __shfl_down(A.y, 1);     // col c0+9
        if (lane == 0)  { l1 = 0.f; l2 = 0.f; }     // image edge zero-pad
        if (lane == 63) { r1 = 0.f; r2 = 0.f; }
        float e[12] = { l2, l1, A.x, A.y, A.z, A.w,
                        Bq.x, Bq.y, Bq.z, Bq.w, r1, r2 };
        unsigned m = 0;
#pragma unroll
        for (int c = 0; c < 8; ++c)
            if (max5(e[c], e[c+1], e[c+2], e[c+3], e[c+4]) > 0.f) m |= 1u << c;
        mrow[r] = m;
    }
}

// ---------------------------------------------------------------------------
// Kernel 1: dilation + histogram (+ optional mask persist).
// Grid (64 bands x 32 batches) = 2048 blocks, 8 blocks/CU.
// Block = 4 waves; wave = 2 rows x 512 cols; lane = 8 cols.
// ---------------------------------------------------------------------------
__global__ __launch_bounds__(256, 8) void k_hist(const float* __restrict__ labels,
                                                 const float* __restrict__ images,
                                                 int* __restrict__ hist,
                                                 unsigned* __restrict__ maskbuf,
                                                 int use_mask) {
    __shared__ int s_hist[NBINS];
    const int tid   = threadIdx.x;
    const int lane  = tid & 63;
    const int w     = tid >> 6;
    const int band  = blockIdx.x;           // 0..63 (8-row bands)
    const int b     = blockIdx.y;
    const int rbase = band * 8 + w * 2;
    const int c0    = lane * 8;
    const float* lab = labels + (size_t)b * HW_;
    const float* img = images + (size_t)b * HW_;

    s_hist[tid] = 0;
    __syncthreads();

    unsigned mrow[2];
    dilate2(lab, rbase, c0, lane, mrow);

#pragma unroll
    for (int r = 0; r < 2; ++r) {
        unsigned m = mrow[r];
        size_t off = (size_t)(rbase + r) * W_ + c0;
        if (m & 0xFu) {
            float4 iv = *(const float4*)(img + off);
            if (m & 1u) atomicAdd(&s_hist[bin_of(iv.x)], 1);
            if (m & 2u) atomicAdd(&s_hist[bin_of(iv.y)], 1);
            if (m & 4u) atomicAdd(&s_hist[bin_of(iv.z)], 1);
            if (m & 8u) atomicAdd(&s_hist[bin_of(iv.w)], 1);
        }
        if (m >> 4) {
            float4 iv = *(const float4*)(img + off + 4);
            if (m & 16u)  atomicAdd(&s_hist[bin_of(iv.x)], 1);
            if (m & 32u)  atomicAdd(&s_hist[bin_of(iv.y)], 1);
            if (m & 64u)  atomicAdd(&s_hist[bin_of(iv.z)], 1);
            if (m & 128u) atomicAdd(&s_hist[bin_of(iv.w)], 1);
        }
        if (use_mask) {                     // pack 4 lanes' 8-bit groups -> u32
            unsigned word = m << ((lane & 3) * 8);
            word |= __shfl_xor(word, 1);
            word |= __shfl_xor(word, 2);
            if ((lane & 3) == 0)
                maskbuf[((size_t)b * H_ + rbase + r) * 16 + (lane >> 2)] = word;
        }
    }
    __syncthreads();
    int c = s_hist[tid];
    if (c) atomicAdd(&hist[b * NBINS + tid], c);
}

// ---------------------------------------------------------------------------
// Kernel 2: scan + two-threshold Otsu argmax (8 i-slices x 32 batches).
// ---------------------------------------------------------------------------
__global__ __launch_bounds__(256) void k_search(const int* __restrict__ hist,
                                                unsigned long long* __restrict__ packed,
                                                float* __restrict__ sm) {
    __shared__ float sA[NBINS];
    __shared__ float sB[NBINS];
    __shared__ float sPQ[NBINS][2];
    __shared__ float sT0[32];
    __shared__ float sT2[NBINS];
    __shared__ int   s_int[256];
    __shared__ unsigned long long s_pack[256];

    const int tid   = threadIdx.x;
    const int slice = blockIdx.x;
    const int b     = blockIdx.y;
    const float s   = 1e-8f;

    int h = hist[b * NBINS + tid];
    s_int[tid] = h;
    __syncthreads();
    for (int off = 128; off > 0; off >>= 1) {       // exact: integer counts
        if (tid < off) s_int[tid] += s_int[tid + off];
        __syncthreads();
    }
    const float ftot = (float)s_int[0];
    __syncthreads();

    float p = (float)h / ftot;
    sPQ[tid][0] = p;
    sPQ[tid][1] = p * (float)tid;
    __syncthreads();

    if (tid == 0) {                  // sequential fold == reference cumsum order
        float ch = 0.0f, cm = 0.0f;
#pragma unroll 8
        for (int i = 0; i < NBINS; ++i) {
            ch += sPQ[i][0];
            cm += sPQ[i][1];
            sA[i] = ch;
            sB[i] = cm;
        }
    }
    __syncthreads();

    const float tm = sB[NBINS - 1];
    if (tid < NT) {
        float cb = sA[tid];
        float w2 = 1.0f - cb;
        float mean2 = (tm - sB[tid]) / (w2 + s);
        float d2 = mean2 - tm;
        sT2[tid] = w2 * (d2 * d2);
    }
    const int i0 = slice * 32;
    if (tid < 32) {
        int i = i0 + tid;
        if (i < NT) {
            float w0 = sA[i];
            float mean0 = sB[i] / (w0 + s);
            float d0 = mean0 - tm;
            sT0[tid] = w0 * (d0 * d0);
        }
    }
    __syncthreads();

    unsigned long long best = 0ull;
    if (tid < NT) {
        const float cb  = sA[tid];
        const float m1v = sB[tid];
        const float w2  = 1.0f - cb;
        const float t2v = sT2[tid];
#pragma unroll 4
        for (int il = 0; il < 32; ++il) {
            int i = i0 + il;
            if (i >= NT) break;
            float w0 = sA[i];
            float w1 = cb - w0;
            float mean1 = (m1v - sB[i]) / (w1 + s);
            float d1 = mean1 - tm;
            float bv = (sT0[il] + w1 * (d1 * d1)) + t2v;
            bool ok = (w0 > 0.f) && (w1 > 0.f) && (w2 > 0.f);
            bv = ok ? bv : 0.0f;
            unsigned k = (unsigned)(i * NT + tid);
            // bv >= 0: float-bit order == value order; ~k => first-max tie-break
            unsigned long long pk =
                ((unsigned long long)__float_as_uint(bv) << 32) | (0xFFFFFFFFu - k);
            best = pk > best ? pk : best;
        }
    }
    s_pack[tid] = best;
    __syncthreads();
    for (int off = 128; off > 0; off >>= 1) {
        if (tid < off) {
            unsigned long long o = s_pack[tid + off];
            if (o > s_pack[tid]) s_pack[tid] = o;
        }
        __syncthreads();
    }
    if (tid == 0) {
        atomicMax(&packed[b], s_pack[0]);
        if (slice == 0) sm[b] = ftot;
    }
}

// ---------------------------------------------------------------------------
// Loss epilogue shared by both k_loss variants
// ---------------------------------------------------------------------------
__device__ __forceinline__ float loss_rows(const float* img, const float* prd,
                                           const unsigned mrow[2], int rbase,
                                           int c0, float t1, float t2) {
    float acc = 0.0f;
#pragma unroll
    for (int r = 0; r < 2; ++r) {
        unsigned m = mrow[r];
        size_t off = (size_t)(rbase + r) * W_ + c0;
        if (m & 0xFu) {
            float4 iv = *(const float4*)(img + off);
            float4 pv = *(const float4*)(prd + off);
            if (m & 1u) { float ci = iv.x >= t2 ? 1.f : (iv.x >= t1 ? 0.5f : 0.f); float d = ci - pv.x; acc += d * d; }
            if (m & 2u) { float ci = iv.y >= t2 ? 1.f : (iv.y >= t1 ? 0.5f : 0.f); float d = ci - pv.y; acc += d * d; }
            if (m & 4u) { float ci = iv.z >= t2 ? 1.f : (iv.z >= t1 ? 0.5f : 0.f); float d = ci - pv.z; acc += d * d; }
            if (m & 8u) { float ci = iv.w >= t2 ? 1.f : (iv.w >= t1 ? 0.5f : 0.f); float d = ci - pv.w; acc += d * d; }
        }
        if (m >> 4) {
            float4 iv = *(const float4*)(img + off + 4);
            float4 pv = *(const float4*)(prd + off + 4);
            if (m & 16u)  { float ci = iv.x >= t2 ? 1.f : (iv.x >= t1 ? 0.5f : 0.f); float d = ci - pv.x; acc += d * d; }
            if (m & 32u)  { float ci = iv.y >= t2 ? 1.f : (iv.y >= t1 ? 0.5f : 0.f); float d = ci - pv.y; acc += d * d; }
            if (m & 64u)  { float ci = iv.z >= t2 ? 1.f : (iv.z >= t1 ? 0.5f : 0.f); float d = ci - pv.z; acc += d * d; }
            if (m & 128u) { float ci = iv.w >= t2 ? 1.f : (iv.w >= t1 ? 0.5f : 0.f); float d = ci - pv.w; acc += d * d; }
        }
    }
    return acc;
}

__device__ __forceinline__ void loss_tail(float acc, int b, float* s_red,
                                          int* s_ticket, float* sq,
                                          const float* sm, int* counter,
                                          float* out, int nblocks) {
    const int tid = threadIdx.x;
    s_red[tid] = acc;
    __syncthreads();
    for (int off = 128; off > 0; off >>= 1) {
        if (tid < off) s_red[tid] += s_red[tid + off];
        __syncthreads();
    }
    if (tid == 0) {
        atomicAdd(&sq[b], s_red[0]);
        __threadfence();
        *s_ticket = atomicAdd(counter, 1);
    }
    __syncthreads();
    if (*s_ticket == nblocks - 1) {         // last block: valid-batch mean
        if (tid < 64) {
            float lp = 0.0f, vc = 0.0f;
            if (tid < B_) {
                float sqv = atomicAdd(&sq[tid], 0.0f);   // coherent read
                float smv = sm[tid] + 1e-8f;
                if (smv > 1e-8f) { lp = sqv / smv; vc = 1.0f; }
            }
            for (int o = 32; o > 0; o >>= 1) {
                lp += __shfl_down(lp, o);
                vc += __shfl_down(vc, o);
            }
            if (tid == 0) out[0] = vc > 0.0f ? lp / fmaxf(vc, 1.0f) : 0.0f;
        }
    }
}

// ---------------------------------------------------------------------------
// Kernel 3a: loss from persisted mask bitmask (no label re-read)
// ---------------------------------------------------------------------------
__global__ __launch_bounds__(256, 8) void k_loss_m(const float* __restrict__ images,
                                                   const float* __restrict__ preds,
                                                   const unsigned* __restrict__ maskbuf,
                                                   const unsigned long long* __restrict__ packed,
                                                   float* __restrict__ sq,
                                                   const float* __restrict__ sm,
                                                   int* __restrict__ counter,
                                                   float* __restrict__ out) {
    __shared__ float s_red[256];
    __shared__ int   s_ticket;
    const int tid   = threadIdx.x;
    const int lane  = tid & 63;
    const int w     = tid >> 6;
    const int band  = blockIdx.x;
    const int b     = blockIdx.y;
    const int rbase = band * 8 + w * 2;
    const int c0    = lane * 8;
    const float* img = images + (size_t)b * HW_;
    const float* prd = preds  + (size_t)b * HW_;

    unsigned long long pk = packed[b];
    unsigned am = 0xFFFFFFFFu - (unsigned)(pk & 0xFFFFFFFFull);
    const float t1 = (float)((int)(am / NT) + 1) / 255.0f;
    const float t2 = (float)((int)(am % NT) + 1) / 255.0f;

    unsigned mrow[2];
#pragma unroll
    for (int r = 0; r < 2; ++r) {
        unsigned word = maskbuf[((size_t)b * H_ + rbase + r) * 16 + (lane >> 2)];
        mrow[r] = (word >> ((lane & 3) * 8)) & 0xFFu;
    }
    float acc = loss_rows(img, prd, mrow, rbase, c0, t1, t2);
    loss_tail(acc, b, s_red, &s_ticket, sq, sm, counter, out, 64 * B_);
}

// ---------------------------------------------------------------------------
// Kernel 3b: loss recomputing dilation (fallback when ws too small)
// ---------------------------------------------------------------------------
__global__ __launch_bounds__(256, 8) void k_loss_r(const float* __restrict__ labels,
                                                   const float* __restrict__ images,
                                                   const float* __restrict__ preds,
                                                   const unsigned long long* __restrict__ packed,
                                                   float* __restrict__ sq,
                                                   const float* __restrict__ sm,
                                                   int* __restrict__ counter,
                                                   float* __restrict__ out) {
    __shared__ float s_red[256];
    __shared__ int   s_ticket;
    const int tid   = threadIdx.x;
    const int lane  = tid & 63;
    const int w     = tid >> 6;
    const int band  = blockIdx.x;
    const int b     = blockIdx.y;
    const int rbase = band * 8 + w * 2;
    const int c0    = lane * 8;
    const float* lab = labels + (size_t)b * HW_;
    const float* img = images + (size_t)b * HW_;
    const float* prd = preds  + (size_t)b * HW_;

    unsigned long long pk = packed[b];
    unsigned am = 0xFFFFFFFFu - (unsigned)(pk & 0xFFFFFFFFull);
    const float t1 = (float)((int)(am / NT) + 1) / 255.0f;
    const float t2 = (float)((int)(am % NT) + 1) / 255.0f;

    unsigned mrow[2];
    dilate2(lab, rbase, c0, lane, mrow);
    float acc = loss_rows(img, prd, mrow, rbase, c0, t1, t2);
    loss_tail(acc, b, s_red, &s_ticket, sq, sm, counter, out, 64 * B_);
}

extern "C" void kernel_launch(void* const* d_in, const int* in_sizes, int n_in,
                              void* d_out, int out_size, void* d_ws, size_t ws_size,
                              hipStream_t stream) {
    const float* preds  = (const float*)d_in[0];
    const float* labels = (const float*)d_in[1];
    const float* images = (const float*)d_in[2];
    float* out = (float*)d_out;

    char* ws = (char*)d_ws;
    int*                hist    = (int*)ws;
    unsigned long long* packed  = (unsigned long long*)(ws + 32768);
    float*              sq      = (float*)(ws + 33024);
    float*              sm      = (float*)(ws + 33152);
    int*                counter = (int*)(ws + 33280);
    unsigned*           maskbuf = (unsigned*)(ws + MASK_OFF);
    const int use_mask = (ws_size >= (size_t)WS_NEEDED) ? 1 : 0;

    hipMemsetAsync(ws, 0, 33296, stream);   // hist + packed + sq + counter

    dim3 gdil(64, B_);                      // 2048 blocks, 8 blocks/CU
    k_hist<<<gdil, 256, 0, stream>>>(labels, images, hist, maskbuf, use_mask);
    k_search<<<dim3(8, B_), 256, 0, stream>>>(hist, packed, sm);
    if (use_mask)
        k_loss_m<<<gdil, 256, 0, stream>>>(images, preds, maskbuf, packed,
                                           sq, sm, counter, out);
    else
        k_loss_r<<<gdil, 256, 0, stream>>>(labels, images, preds, packed,
                                           sq, sm, counter, out);
}

// Round 5
// 176.274 us; speedup vs baseline: 3.3146x; 1.0521x over previous
//
#include <hip/hip_runtime.h>
#include <math.h>

#define B_    32
#define H_    512
#define W_    512
#define NBINS 256
#define NT    254
#define HW_   (H_ * W_)
#define MAGIC 0x13371337

// ws layout (all memset 0 at launch):
//   [0     .. 32768)  int   hist[32][256]   Otsu histogram (bin_of binning)
//   [32768 .. 65536)  int   g0[32][256]     masked-count per q-bucket (0..254)
//   [65536 .. 98304)  float g1[32][256]     sum of pred per q-bucket
//   [98304 .. 98432)  float p2[32]          sum of pred^2 over masked px
//   [98432 .. 98560)  int   flags[32]
//   [98560 .. 98688)  float lp[32]          per-batch loss
//   [98688 .. 98816)  float totf[32]        per-batch mask count
#define WS_ZERO 98816

__device__ __forceinline__ float max5(float a, float b, float c, float d, float e) {
    return fmaxf(fmaxf(fmaxf(a, b), fmaxf(c, d)), e);
}
__device__ __forceinline__ float4 fmax4(float4 a, float4 b) {
    return make_float4(fmaxf(a.x, b.x), fmaxf(a.y, b.y),
                       fmaxf(a.z, b.z), fmaxf(a.w, b.w));
}
__device__ __forceinline__ int bin_of(float im) {
    float v = im * 255.0f;                  // reference: v = imgs*255
    float u = v * (256.0f / 255.0f);        // reference: v*(NBINS/255.0) in f32
    int bin = (int)floorf(u);
    return bin < 0 ? 0 : (bin > NBINS - 1 ? NBINS - 1 : bin);
}

// Dilated-mask bits (5x5 max > 0) for 2 rows x 8 cols owned by (rbase, c0).
// Validated bit-exact in R2-R4.
__device__ __forceinline__ void dilate2(const float* __restrict__ lab,
                                        int rbase, int c0, int lane,
                                        unsigned mrow[2]) {
    float4 A0 = make_float4(0.f, 0.f, 0.f, 0.f), B0 = A0, A1 = A0, B1 = A0;
#pragma unroll
    for (int k = 0; k < 6; ++k) {
        int gr = rbase - 2 + k;
        float4 la = make_float4(0.f, 0.f, 0.f, 0.f), lb = la;
        if ((unsigned)gr < (unsigned)H_) {
            la = *(const float4*)(lab + gr * W_ + c0);
            lb = *(const float4*)(lab + gr * W_ + c0 + 4);
        }
        if (k < 5) { A0 = fmax4(A0, la); B0 = fmax4(B0, lb); }
        if (k > 0) { A1 = fmax4(A1, la); B1 = fmax4(B1, lb); }
    }
#pragma unroll
    for (int r = 0; r < 2; ++r) {
        float4 A  = r ? A1 : A0;
        float4 Bq = r ? B1 : B0;
        float l2 = __shfl_up(Bq.z, 1);
        float l1 = __shfl_up(Bq.w, 1);
        float r1 = __shfl_down(A.x, 1);
        float r2 = __shfl_down(A.y, 1);
        if (lane == 0)  { l1 = 0.f; l2 = 0.f; }
        if (lane == 63) { r1 = 0.f; r2 = 0.f; }
        float e[12] = { l2, l1, A.x, A.y, A.z, A.w,
                        Bq.x, Bq.y, Bq.z, Bq.w, r1, r2 };
        unsigned m = 0;
#pragma unroll
        for (int c = 0; c < 8; ++c)
            if (max5(e[c], e[c+1], e[c+2], e[c+3], e[c+4]) > 0.f) m |= 1u << c;
        mrow[r] = m;
    }
}

// Per-pixel accumulate: Otsu hist + exact q-bucket (count, sum-p) + sum p^2.
// q = #{k in [1..254] : im >= f32(k/255)} via floor + exact +/-1 adjust.
__device__ __forceinline__ void px_acc(unsigned m, unsigned bit, float im, float p,
                                       int* s_hist, int* s_g0, float* s_g1,
                                       const float* s_thr, float& p2a) {
    if (m & bit) {
        atomicAdd(&s_hist[bin_of(im)], 1);
        int q0 = (int)(im * 255.0f);
        if (q0 > 254) q0 = 254;
        int q = q0;
        if (q0 < 254 && im >= s_thr[q0 + 1]) q = q0 + 1;
        else if (q0 > 0 && im < s_thr[q0])   q = q0 - 1;
        atomicAdd(&s_g0[q], 1);
        atomicAdd(&s_g1[q], p);
        p2a += p * p;
    }
}

// ---------------------------------------------------------------------------
// Kernel 1: single dense pass. Dilation + Otsu hist + loss-sufficient stats.
// Grid (64 bands x 32 batches) = 2048 blocks; all loads dense/coalesced.
// ---------------------------------------------------------------------------
__global__ __launch_bounds__(256, 8) void k_main(const float* __restrict__ labels,
                                                 const float* __restrict__ images,
                                                 const float* __restrict__ preds,
                                                 int* __restrict__ hist,
                                                 int* __restrict__ g0,
                                                 float* __restrict__ g1,
                                                 float* __restrict__ p2) {
    __shared__ int   s_hist[NBINS];
    __shared__ int   s_g0[NBINS];
    __shared__ float s_g1[NBINS];
    __shared__ float s_thr[NBINS];
    __shared__ float s_red[256];

    const int tid   = threadIdx.x;
    const int lane  = tid & 63;
    const int w     = tid >> 6;
    const int band  = blockIdx.x;           // 0..63 (8-row bands)
    const int b     = blockIdx.y;
    const int rbase = band * 8 + w * 2;
    const int c0    = lane * 8;
    const float* lab = labels + (size_t)b * HW_;
    const float* img = images + (size_t)b * HW_;
    const float* prd = preds  + (size_t)b * HW_;

    s_hist[tid] = 0;
    s_g0[tid]   = 0;
    s_g1[tid]   = 0.0f;
    s_thr[tid]  = (float)tid / 255.0f;      // f32 RN, matches reference t-values
    __syncthreads();

    unsigned mrow[2];
    dilate2(lab, rbase, c0, lane, mrow);

    float p2a = 0.0f;
#pragma unroll
    for (int r = 0; r < 2; ++r) {
        unsigned m = mrow[r];
        size_t off = (size_t)(rbase + r) * W_ + c0;
        // dense, unconditional loads (sparse-load MLP collapse measured in R4)
        float4 iv0 = *(const float4*)(img + off);
        float4 iv1 = *(const float4*)(img + off + 4);
        float4 pv0 = *(const float4*)(prd + off);
        float4 pv1 = *(const float4*)(prd + off + 4);
        px_acc(m,   1u, iv0.x, pv0.x, s_hist, s_g0, s_g1, s_thr, p2a);
        px_acc(m,   2u, iv0.y, pv0.y, s_hist, s_g0, s_g1, s_thr, p2a);
        px_acc(m,   4u, iv0.z, pv0.z, s_hist, s_g0, s_g1, s_thr, p2a);
        px_acc(m,   8u, iv0.w, pv0.w, s_hist, s_g0, s_g1, s_thr, p2a);
        px_acc(m,  16u, iv1.x, pv1.x, s_hist, s_g0, s_g1, s_thr, p2a);
        px_acc(m,  32u, iv1.y, pv1.y, s_hist, s_g0, s_g1, s_thr, p2a);
        px_acc(m,  64u, iv1.z, pv1.z, s_hist, s_g0, s_g1, s_thr, p2a);
        px_acc(m, 128u, iv1.w, pv1.w, s_hist, s_g0, s_g1, s_thr, p2a);
    }

    s_red[tid] = p2a;
    __syncthreads();

    {   // flush per-block histograms (device-scope atomics)
        int c = s_hist[tid];
        if (c) atomicAdd(&hist[b * NBINS + tid], c);
        int c2 = s_g0[tid];
        if (c2) atomicAdd(&g0[b * NBINS + tid], c2);
        float gv = s_g1[tid];
        if (gv != 0.0f) atomicAdd(&g1[b * NBINS + tid], gv);
    }
    for (int off = 128; off > 0; off >>= 1) {
        if (tid < off) s_red[tid] += s_red[tid + off];
        __syncthreads();
    }
    if (tid == 0 && s_red[0] != 0.0f) atomicAdd(&p2[b], s_red[0]);
}

// ---------------------------------------------------------------------------
// Kernel 2: blocks 0..31 = per-batch Otsu argmax (bit-exact R2 arithmetic)
//           + f64 loss evaluation from suffix sums. Block 32 = final combine.
// ---------------------------------------------------------------------------
__global__ __launch_bounds__(256) void k_search(const int* __restrict__ hist,
                                                const int* __restrict__ g0,
                                                const float* __restrict__ g1,
                                                const float* __restrict__ p2,
                                                int* __restrict__ flags,
                                                float* __restrict__ lp,
                                                float* __restrict__ totf,
                                                float* __restrict__ out) {
    const int tid = threadIdx.x;

    if (blockIdx.x == 32) {                 // final combiner
        if (tid < B_) {
            while (__hip_atomic_load(&flags[tid], __ATOMIC_ACQUIRE,
                                     __HIP_MEMORY_SCOPE_AGENT) != MAGIC)
                __builtin_amdgcn_s_sleep(2);
        }
        __syncthreads();
        if (tid == 0) {
            float sum = 0.0f;
            int   cnt = 0;
            for (int b = 0; b < B_; ++b) {
                float t = __hip_atomic_load(&totf[b], __ATOMIC_RELAXED,
                                            __HIP_MEMORY_SCOPE_AGENT);
                float l = __hip_atomic_load(&lp[b], __ATOMIC_RELAXED,
                                            __HIP_MEMORY_SCOPE_AGENT);
                float smv = t + 1e-8f;
                if (smv > 1e-8f) { sum += l; cnt += 1; }
            }
            out[0] = cnt > 0 ? sum / fmaxf((float)cnt, 1.0f) : 0.0f;
        }
        return;
    }

    __shared__ float  sA[NBINS];
    __shared__ float  sB[NBINS];
    __shared__ float  sPQ[NBINS][2];
    __shared__ float  sT0[NBINS];
    __shared__ float  sT2[NBINS];
    __shared__ int    s_int[256];
    __shared__ unsigned long long s_pack[256];
    __shared__ double sD0[256];
    __shared__ double sD1[256];
    __shared__ double s_res[4];
    __shared__ int    s_am;

    const int b   = blockIdx.x;
    const float s = 1e-8f;

    int h = hist[b * NBINS + tid];
    s_int[tid] = h;
    __syncthreads();
    for (int off = 128; off > 0; off >>= 1) {       // exact: integer counts
        if (tid < off) s_int[tid] += s_int[tid + off];
        __syncthreads();
    }
    const int   tot  = s_int[0];
    const float ftot = (float)tot;
    __syncthreads();

    float p = (float)h / ftot;
    sPQ[tid][0] = p;
    sPQ[tid][1] = p * (float)tid;
    __syncthreads();

    if (tid == 0) {                  // sequential fold == reference cumsum order
        float ch = 0.0f, cm = 0.0f;
#pragma unroll 8
        for (int i = 0; i < NBINS; ++i) {
            ch += sPQ[i][0];
            cm += sPQ[i][1];
            sA[i] = ch;
            sB[i] = cm;
        }
    }
    __syncthreads();

    const float tm = sB[NBINS - 1];
    if (tid < NT) {
        float cb = sA[tid];
        float w2 = 1.0f - cb;
        float mean2 = (tm - sB[tid]) / (w2 + s);
        float d2 = mean2 - tm;
        sT2[tid] = w2 * (d2 * d2);

        float w0 = sA[tid];
        float mean0 = sB[tid] / (w0 + s);
        float d0 = mean0 - tm;
        sT0[tid] = w0 * (d0 * d0);
    }
    __syncthreads();

    unsigned long long best = 0ull;
    if (tid < NT) {
        const float cb  = sA[tid];
        const float m1v = sB[tid];
        const float w2  = 1.0f - cb;
        const float t2v = sT2[tid];
#pragma unroll 4
        for (int i = 0; i < NT; ++i) {
            float w0 = sA[i];
            float w1 = cb - w0;
            float mean1 = (m1v - sB[i]) / (w1 + s);
            float d1 = mean1 - tm;
            float bv = (sT0[i] + w1 * (d1 * d1)) + t2v;
            bool ok = (w0 > 0.f) && (w1 > 0.f) && (w2 > 0.f);
            bv = ok ? bv : 0.0f;
            unsigned k = (unsigned)(i * NT + tid);
            // bv >= 0: float-bit order == value order; ~k => first-max tie-break
            unsigned long long pk =
                ((unsigned long long)__float_as_uint(bv) << 32) | (0xFFFFFFFFu - k);
            best = pk > best ? pk : best;
        }
    }
    s_pack[tid] = best;
    __syncthreads();
    for (int off = 128; off > 0; off >>= 1) {
        if (tid < off) {
            unsigned long long o = s_pack[tid + off];
            if (o > s_pack[tid]) s_pack[tid] = o;
        }
        __syncthreads();
    }
    if (tid == 0)
        s_am = (int)(0xFFFFFFFFu - (unsigned)(s_pack[0] & 0xFFFFFFFFull));
    __syncthreads();

    const int ti = s_am / NT;
    const int tj = s_am % NT;
    const int v  = ti + 1;                  // im >= t1  <=>  q >= v
    const int wq = tj + 1;                  // im >= t2  <=>  q >= wq

    // f64 suffix sums S0/S1 at v and wq
    int   gc = g0[b * NBINS + tid];
    float gg = g1[b * NBINS + tid];

    sD0[tid] = (tid >= v) ? (double)gc : 0.0;
    sD1[tid] = (tid >= v) ? (double)gg : 0.0;
    __syncthreads();
    for (int off = 128; off > 0; off >>= 1) {
        if (tid < off) { sD0[tid] += sD0[tid + off]; sD1[tid] += sD1[tid + off]; }
        __syncthreads();
    }
    if (tid == 0) { s_res[0] = sD0[0]; s_res[1] = sD1[0]; }
    __syncthreads();

    sD0[tid] = (tid >= wq) ? (double)gc : 0.0;
    sD1[tid] = (tid >= wq) ? (double)gg : 0.0;
    __syncthreads();
    for (int off = 128; off > 0; off >>= 1) {
        if (tid < off) { sD0[tid] += sD0[tid + off]; sD1[tid] += sD1[tid + off]; }
        __syncthreads();
    }

    if (tid == 0) {
        double S0v = s_res[0], S1v = s_res[1];
        double S0w = sD0[0],   S1w = sD1[0];
        double c05, s05;
        if (v <= wq) { c05 = S0v - S0w; s05 = S1v - S1w; }
        else         { c05 = 0.0;       s05 = 0.0; }
        // sum (ci-p)^2 = |A| - 2*S1(A) + 0.25*|B\A| - S1(B\A) + sum p^2
        double sqd = S0w - 2.0 * S1w + 0.25 * c05 - s05 + (double)p2[b];
        float smv = ftot + 1e-8f;
        float lpv = (smv > 1e-8f) ? (float)sqd / smv : 0.0f;
        __hip_atomic_store(&lp[b], lpv, __ATOMIC_RELAXED, __HIP_MEMORY_SCOPE_AGENT);
        __hip_atomic_store(&totf[b], ftot, __ATOMIC_RELAXED, __HIP_MEMORY_SCOPE_AGENT);
        __hip_atomic_store(&flags[b], MAGIC, __ATOMIC_RELEASE, __HIP_MEMORY_SCOPE_AGENT);
    }
}

extern "C" void kernel_launch(void* const* d_in, const int* in_sizes, int n_in,
                              void* d_out, int out_size, void* d_ws, size_t ws_size,
                              hipStream_t stream) {
    const float* preds  = (const float*)d_in[0];
    const float* labels = (const float*)d_in[1];
    const float* images = (const float*)d_in[2];
    float* out = (float*)d_out;

    char* ws = (char*)d_ws;
    int*   hist  = (int*)ws;
    int*   g0    = (int*)(ws + 32768);
    float* g1    = (float*)(ws + 65536);
    float* p2    = (float*)(ws + 98304);
    int*   flags = (int*)(ws + 98432);
    float* lp    = (float*)(ws + 98560);
    float* totf  = (float*)(ws + 98688);

    hipMemsetAsync(ws, 0, WS_ZERO, stream);

    k_main<<<dim3(64, B_), 256, 0, stream>>>(labels, images, preds,
                                             hist, g0, g1, p2);
    k_search<<<33, 256, 0, stream>>>(hist, g0, g1, p2, flags, lp, totf, out);
}

// Round 6
// 151.385 us; speedup vs baseline: 3.8596x; 1.1644x over previous
//
#include <hip/hip_runtime.h>
#include <math.h>

#define B_    32
#define H_    512
#define W_    512
#define NBINS 256
#define NT    254
#define HW_   (H_ * W_)
#define MAGIC 0x13371337

// ---------- big-ws (2-dispatch) layout: per-block partials, no memset ----------
//   [0       .. 2097152)  int   hist_p[2048][256]
//   [2097152 .. 4194304)  int   g0_p[2048][256]
//   [4194304 .. 6291456)  float g1_p[2048][256]
//   [6291456 .. 6299648)  float p2_p[2048]
//   [6299648 .. 6301696)  ull   packed_s[32][8]
//   [6301696 .. 6302720)  int   sflag[32][8]
//   [6302720 .. 6302848)  float lp[32]
//   [6302848 .. 6302976)  float totf[32]
//   [6302976 .. 6303104)  int   flags[32]
// every slot written unconditionally or guarded by MAGIC flags (poison-safe)
#define WS_BIG 6303104

// ---------- small-ws (R5 fallback) layout (memset 0 at launch) ----------
#define WS_ZERO 98816

__device__ __forceinline__ float max5(float a, float b, float c, float d, float e) {
    return fmaxf(fmaxf(fmaxf(a, b), fmaxf(c, d)), e);
}
__device__ __forceinline__ float4 fmax4(float4 a, float4 b) {
    return make_float4(fmaxf(a.x, b.x), fmaxf(a.y, b.y),
                       fmaxf(a.z, b.z), fmaxf(a.w, b.w));
}
__device__ __forceinline__ int bin_of(float im) {
    float v = im * 255.0f;                  // reference: v = imgs*255
    float u = v * (256.0f / 255.0f);        // reference: v*(NBINS/255.0) in f32
    int bin = (int)floorf(u);
    return bin < 0 ? 0 : (bin > NBINS - 1 ? NBINS - 1 : bin);
}

// Dilated-mask bits (5x5 max > 0) for 2 rows x 8 cols. Validated R2-R5.
__device__ __forceinline__ void dilate2(const float* __restrict__ lab,
                                        int rbase, int c0, int lane,
                                        unsigned mrow[2]) {
    float4 A0 = make_float4(0.f, 0.f, 0.f, 0.f), B0 = A0, A1 = A0, B1 = A0;
#pragma unroll
    for (int k = 0; k < 6; ++k) {
        int gr = rbase - 2 + k;
        float4 la = make_float4(0.f, 0.f, 0.f, 0.f), lb = la;
        if ((unsigned)gr < (unsigned)H_) {
            la = *(const float4*)(lab + gr * W_ + c0);
            lb = *(const float4*)(lab + gr * W_ + c0 + 4);
        }
        if (k < 5) { A0 = fmax4(A0, la); B0 = fmax4(B0, lb); }
        if (k > 0) { A1 = fmax4(A1, la); B1 = fmax4(B1, lb); }
    }
#pragma unroll
    for (int r = 0; r < 2; ++r) {
        float4 A  = r ? A1 : A0;
        float4 Bq = r ? B1 : B0;
        float l2 = __shfl_up(Bq.z, 1);
        float l1 = __shfl_up(Bq.w, 1);
        float r1 = __shfl_down(A.x, 1);
        float r2 = __shfl_down(A.y, 1);
        if (lane == 0)  { l1 = 0.f; l2 = 0.f; }
        if (lane == 63) { r1 = 0.f; r2 = 0.f; }
        float e[12] = { l2, l1, A.x, A.y, A.z, A.w,
                        Bq.x, Bq.y, Bq.z, Bq.w, r1, r2 };
        unsigned m = 0;
#pragma unroll
        for (int c = 0; c < 8; ++c)
            if (max5(e[c], e[c+1], e[c+2], e[c+3], e[c+4]) > 0.f) m |= 1u << c;
        mrow[r] = m;
    }
}

// Per-pixel accumulate (validated R5): Otsu hist + exact q-bucket + sum p^2.
__device__ __forceinline__ void px_acc(unsigned m, unsigned bit, float im, float p,
                                       int* s_hist, int* s_g0, float* s_g1,
                                       const float* s_thr, float& p2a) {
    if (m & bit) {
        atomicAdd(&s_hist[bin_of(im)], 1);
        int q0 = (int)(im * 255.0f);
        if (q0 > 254) q0 = 254;
        int q = q0;
        if (q0 < 254 && im >= s_thr[q0 + 1]) q = q0 + 1;
        else if (q0 > 0 && im < s_thr[q0])   q = q0 - 1;
        atomicAdd(&s_g0[q], 1);
        atomicAdd(&s_g1[q], p);
        p2a += p * p;
    }
}

// shared body: accumulate block-local s_hist/s_g0/s_g1 and p2 partial
__device__ __forceinline__ float main_body(const float* lab, const float* img,
                                           const float* prd, int band,
                                           int* s_hist, int* s_g0, float* s_g1,
                                           const float* s_thr) {
    const int tid   = threadIdx.x;
    const int lane  = tid & 63;
    const int w     = tid >> 6;
    const int rbase = band * 8 + w * 2;
    const int c0    = lane * 8;

    unsigned mrow[2];
    dilate2(lab, rbase, c0, lane, mrow);

    float p2a = 0.0f;
#pragma unroll
    for (int r = 0; r < 2; ++r) {
        unsigned m = mrow[r];
        size_t off = (size_t)(rbase + r) * W_ + c0;
        float4 iv0 = *(const float4*)(img + off);
        float4 iv1 = *(const float4*)(img + off + 4);
        float4 pv0 = *(const float4*)(prd + off);
        float4 pv1 = *(const float4*)(prd + off + 4);
        px_acc(m,   1u, iv0.x, pv0.x, s_hist, s_g0, s_g1, s_thr, p2a);
        px_acc(m,   2u, iv0.y, pv0.y, s_hist, s_g0, s_g1, s_thr, p2a);
        px_acc(m,   4u, iv0.z, pv0.z, s_hist, s_g0, s_g1, s_thr, p2a);
        px_acc(m,   8u, iv0.w, pv0.w, s_hist, s_g0, s_g1, s_thr, p2a);
        px_acc(m,  16u, iv1.x, pv1.x, s_hist, s_g0, s_g1, s_thr, p2a);
        px_acc(m,  32u, iv1.y, pv1.y, s_hist, s_g0, s_g1, s_thr, p2a);
        px_acc(m,  64u, iv1.z, pv1.z, s_hist, s_g0, s_g1, s_thr, p2a);
        px_acc(m, 128u, iv1.w, pv1.w, s_hist, s_g0, s_g1, s_thr, p2a);
    }
    return p2a;
}

// ===========================================================================
// PATH A (2 dispatches): k_main_p writes per-block partial slots (no atomics,
// no pre-zeroed ws); k_search_p reduces partials + Otsu + loss + combine.
// ===========================================================================
__global__ __launch_bounds__(256, 8) void k_main_p(const float* __restrict__ labels,
                                                   const float* __restrict__ images,
                                                   const float* __restrict__ preds,
                                                   int* __restrict__ hist_p,
                                                   int* __restrict__ g0_p,
                                                   float* __restrict__ g1_p,
                                                   float* __restrict__ p2_p) {
    __shared__ int   s_hist[NBINS];
    __shared__ int   s_g0[NBINS];
    __shared__ float s_g1[NBINS];
    __shared__ float s_thr[NBINS];
    __shared__ float s_red[256];

    const int tid  = threadIdx.x;
    const int band = blockIdx.x;            // 0..63
    const int b    = blockIdx.y;            // 0..31
    const int slot = b * 64 + band;
    const float* lab = labels + (size_t)b * HW_;
    const float* img = images + (size_t)b * HW_;
    const float* prd = preds  + (size_t)b * HW_;

    s_hist[tid] = 0;
    s_g0[tid]   = 0;
    s_g1[tid]   = 0.0f;
    s_thr[tid]  = (float)tid / 255.0f;
    __syncthreads();

    float p2a = main_body(lab, img, prd, band, s_hist, s_g0, s_g1, s_thr);

    s_red[tid] = p2a;
    __syncthreads();
    // plain stores to this block's own slot (every slot written -> poison-safe)
    hist_p[(slot << 8) + tid] = s_hist[tid];
    g0_p  [(slot << 8) + tid] = s_g0[tid];
    g1_p  [(slot << 8) + tid] = s_g1[tid];
    for (int off = 128; off > 0; off >>= 1) {
        if (tid < off) s_red[tid] += s_red[tid + off];
        __syncthreads();
    }
    if (tid == 0) p2_p[slot] = s_red[0];
}

__global__ __launch_bounds__(256) void k_search_p(const int* __restrict__ hist_p,
                                                  const int* __restrict__ g0_p,
                                                  const float* __restrict__ g1_p,
                                                  const float* __restrict__ p2_p,
                                                  unsigned long long* __restrict__ packed_s,
                                                  int* __restrict__ sflag,
                                                  float* __restrict__ lp,
                                                  float* __restrict__ totf,
                                                  int* __restrict__ flags,
                                                  float* __restrict__ out) {
    const int tid = threadIdx.x;

    if (blockIdx.x == 256) {                // final combiner
        if (tid < B_) {
            while (__hip_atomic_load(&flags[tid], __ATOMIC_ACQUIRE,
                                     __HIP_MEMORY_SCOPE_AGENT) != MAGIC)
                __builtin_amdgcn_s_sleep(2);
        }
        __syncthreads();
        if (tid == 0) {
            float sum = 0.0f;
            int   cnt = 0;
            for (int b = 0; b < B_; ++b) {
                float t = __hip_atomic_load(&totf[b], __ATOMIC_RELAXED,
                                            __HIP_MEMORY_SCOPE_AGENT);
                float l = __hip_atomic_load(&lp[b], __ATOMIC_RELAXED,
                                            __HIP_MEMORY_SCOPE_AGENT);
                float smv = t + 1e-8f;
                if (smv > 1e-8f) { sum += l; cnt += 1; }
            }
            out[0] = cnt > 0 ? sum / fmaxf((float)cnt, 1.0f) : 0.0f;
        }
        return;
    }

    __shared__ float  sA[NBINS];
    __shared__ float  sB[NBINS];
    __shared__ float  sPQ[NBINS][2];
    __shared__ float  sT0[32];
    __shared__ float  sT2[NBINS];
    __shared__ int    s_int[256];
    __shared__ unsigned long long s_pack[256];
    __shared__ double sD0[256];
    __shared__ double sD1[256];
    __shared__ double s_res[4];

    const int slice = blockIdx.x & 7;
    const int b     = blockIdx.x >> 3;
    const float s   = 1e-8f;

    // reduce 64 band-partials -> this batch's histogram bin `tid`
    int h = 0;
    {
        const int* hp = hist_p + ((b * 64) << 8) + tid;
#pragma unroll 8
        for (int band = 0; band < 64; ++band) h += hp[band << 8];
    }
    s_int[tid] = h;
    __syncthreads();
    for (int off = 128; off > 0; off >>= 1) {       // exact: integer counts
        if (tid < off) s_int[tid] += s_int[tid + off];
        __syncthreads();
    }
    const float ftot = (float)s_int[0];
    __syncthreads();

    float p = (float)h / ftot;
    sPQ[tid][0] = p;
    sPQ[tid][1] = p * (float)tid;
    __syncthreads();

    if (tid == 0) {                  // sequential fold == reference cumsum order
        float ch = 0.0f, cm = 0.0f;
#pragma unroll 8
        for (int i = 0; i < NBINS; ++i) {
            ch += sPQ[i][0];
            cm += sPQ[i][1];
            sA[i] = ch;
            sB[i] = cm;
        }
    }
    __syncthreads();

    const float tm = sB[NBINS - 1];
    if (tid < NT) {
        float cb = sA[tid];
        float w2 = 1.0f - cb;
        float mean2 = (tm - sB[tid]) / (w2 + s);
        float d2 = mean2 - tm;
        sT2[tid] = w2 * (d2 * d2);
    }
    const int i0 = slice * 32;
    if (tid < 32) {
        int i = i0 + tid;
        if (i < NT) {
            float w0 = sA[i];
            float mean0 = sB[i] / (w0 + s);
            float d0 = mean0 - tm;
            sT0[tid] = w0 * (d0 * d0);
        }
    }
    __syncthreads();

    unsigned long long best = 0ull;
    if (tid < NT) {
        const float cb  = sA[tid];
        const float m1v = sB[tid];
        const float w2  = 1.0f - cb;
        const float t2v = sT2[tid];
#pragma unroll 8
        for (int il = 0; il < 32; ++il) {
            int i = i0 + il;
            if (i >= NT) break;
            float w0 = sA[i];
            float w1 = cb - w0;
            float mean1 = (m1v - sB[i]) / (w1 + s);
            float d1 = mean1 - tm;
            float bv = (sT0[il] + w1 * (d1 * d1)) + t2v;
            bool ok = (w0 > 0.f) && (w1 > 0.f) && (w2 > 0.f);
            bv = ok ? bv : 0.0f;
            unsigned k = (unsigned)(i * NT + tid);
            // bv >= 0: float-bit order == value order; ~k => first-max tie-break
            unsigned long long pk =
                ((unsigned long long)__float_as_uint(bv) << 32) | (0xFFFFFFFFu - k);
            best = pk > best ? pk : best;
        }
    }
    s_pack[tid] = best;
    __syncthreads();
    for (int off = 128; off > 0; off >>= 1) {
        if (tid < off) {
            unsigned long long o = s_pack[tid + off];
            if (o > s_pack[tid]) s_pack[tid] = o;
        }
        __syncthreads();
    }
    if (tid == 0) {
        packed_s[b * 8 + slice] = s_pack[0];
        __hip_atomic_store(&sflag[b * 8 + slice], MAGIC,
                           __ATOMIC_RELEASE, __HIP_MEMORY_SCOPE_AGENT);
    }
    if (slice != 0) return;

    // ---- slice-0 block: combine 8 slice maxima, evaluate loss ----
    if (tid < 8 && tid != 0) {
        while (__hip_atomic_load(&sflag[b * 8 + tid], __ATOMIC_ACQUIRE,
                                 __HIP_MEMORY_SCOPE_AGENT) != MAGIC)
            __builtin_amdgcn_s_sleep(2);
    }
    __syncthreads();
    s_pack[tid] = (tid < 8) ? packed_s[b * 8 + tid] : 0ull;
    __syncthreads();
    if (tid < 4) {
        unsigned long long o = s_pack[tid + 4];
        if (o > s_pack[tid]) s_pack[tid] = o;
    }
    __syncthreads();
    if (tid < 2) {
        unsigned long long o = s_pack[tid + 2];
        if (o > s_pack[tid]) s_pack[tid] = o;
    }
    __syncthreads();
    if (tid == 0) {
        unsigned long long o = s_pack[1];
        if (o > s_pack[0]) s_pack[0] = o;
    }
    __syncthreads();
    const int am = (int)(0xFFFFFFFFu - (unsigned)(s_pack[0] & 0xFFFFFFFFull));
    const int v  = am / NT + 1;             // im >= t1  <=>  q >= v
    const int wq = am % NT + 1;             // im >= t2  <=>  q >= wq

    // reduce g0/g1 partials for this batch
    int   gc = 0;
    float gg = 0.0f;
    {
        const int*   gp = g0_p + ((b * 64) << 8) + tid;
        const float* hp = g1_p + ((b * 64) << 8) + tid;
#pragma unroll 8
        for (int band = 0; band < 64; ++band) { gc += gp[band << 8]; gg += hp[band << 8]; }
    }

    // f64 suffix sums S0/S1 at v and wq (validated R5 math)
    sD0[tid] = (tid >= v) ? (double)gc : 0.0;
    sD1[tid] = (tid >= v) ? (double)gg : 0.0;
    __syncthreads();
    for (int off = 128; off > 0; off >>= 1) {
        if (tid < off) { sD0[tid] += sD0[tid + off]; sD1[tid] += sD1[tid + off]; }
        __syncthreads();
    }
    if (tid == 0) { s_res[0] = sD0[0]; s_res[1] = sD1[0]; }
    __syncthreads();

    sD0[tid] = (tid >= wq) ? (double)gc : 0.0;
    sD1[tid] = (tid >= wq) ? (double)gg : 0.0;
    __syncthreads();
    for (int off = 128; off > 0; off >>= 1) {
        if (tid < off) { sD0[tid] += sD0[tid + off]; sD1[tid] += sD1[tid + off]; }
        __syncthreads();
    }
    if (tid == 0) { s_res[2] = sD0[0]; s_res[3] = sD1[0]; }
    __syncthreads();

    // p2 partial reduce (64 values)
    sD0[tid] = (tid < 64) ? (double)p2_p[(b << 6) + tid] : 0.0;
    __syncthreads();
    for (int off = 128; off > 0; off >>= 1) {
        if (tid < off) sD0[tid] += sD0[tid + off];
        __syncthreads();
    }

    if (tid == 0) {
        double S0v = s_res[0], S1v = s_res[1];
        double S0w = s_res[2], S1w = s_res[3];
        double c05 = (v <= wq) ? (S0v - S0w) : 0.0;
        double s05 = (v <= wq) ? (S1v - S1w) : 0.0;
        // sum (ci-p)^2 = |A| - 2*S1(A) + 0.25*|B\A| - S1(B\A) + sum p^2
        double sqd = S0w - 2.0 * S1w + 0.25 * c05 - s05 + sD0[0];
        float smv = ftot + 1e-8f;
        float lpv = (smv > 1e-8f) ? (float)sqd / smv : 0.0f;
        __hip_atomic_store(&lp[b], lpv, __ATOMIC_RELAXED, __HIP_MEMORY_SCOPE_AGENT);
        __hip_atomic_store(&totf[b], ftot, __ATOMIC_RELAXED, __HIP_MEMORY_SCOPE_AGENT);
        __hip_atomic_store(&flags[b], MAGIC, __ATOMIC_RELEASE, __HIP_MEMORY_SCOPE_AGENT);
    }
}

// ===========================================================================
// PATH B (fallback, R5 verbatim semantics): memset + k_main_fb + k_search_fb
// ===========================================================================
__global__ __launch_bounds__(256, 8) void k_main_fb(const float* __restrict__ labels,
                                                    const float* __restrict__ images,
                                                    const float* __restrict__ preds,
                                                    int* __restrict__ hist,
                                                    int* __restrict__ g0,
                                                    float* __restrict__ g1,
                                                    float* __restrict__ p2) {
    __shared__ int   s_hist[NBINS];
    __shared__ int   s_g0[NBINS];
    __shared__ float s_g1[NBINS];
    __shared__ float s_thr[NBINS];
    __shared__ float s_red[256];

    const int tid  = threadIdx.x;
    const int band = blockIdx.x;
    const int b    = blockIdx.y;
    const float* lab = labels + (size_t)b * HW_;
    const float* img = images + (size_t)b * HW_;
    const float* prd = preds  + (size_t)b * HW_;

    s_hist[tid] = 0;
    s_g0[tid]   = 0;
    s_g1[tid]   = 0.0f;
    s_thr[tid]  = (float)tid / 255.0f;
    __syncthreads();

    float p2a = main_body(lab, img, prd, band, s_hist, s_g0, s_g1, s_thr);

    s_red[tid] = p2a;
    __syncthreads();
    {
        int c = s_hist[tid];
        if (c) atomicAdd(&hist[b * NBINS + tid], c);
        int c2 = s_g0[tid];
        if (c2) atomicAdd(&g0[b * NBINS + tid], c2);
        float gv = s_g1[tid];
        if (gv != 0.0f) atomicAdd(&g1[b * NBINS + tid], gv);
    }
    for (int off = 128; off > 0; off >>= 1) {
        if (tid < off) s_red[tid] += s_red[tid + off];
        __syncthreads();
    }
    if (tid == 0 && s_red[0] != 0.0f) atomicAdd(&p2[b], s_red[0]);
}

__global__ __launch_bounds__(256) void k_search_fb(const int* __restrict__ hist,
                                                   const int* __restrict__ g0,
                                                   const float* __restrict__ g1,
                                                   const float* __restrict__ p2,
                                                   int* __restrict__ flags,
                                                   float* __restrict__ lp,
                                                   float* __restrict__ totf,
                                                   float* __restrict__ out) {
    const int tid = threadIdx.x;

    if (blockIdx.x == 32) {
        if (tid < B_) {
            while (__hip_atomic_load(&flags[tid], __ATOMIC_ACQUIRE,
                                     __HIP_MEMORY_SCOPE_AGENT) != MAGIC)
                __builtin_amdgcn_s_sleep(2);
        }
        __syncthreads();
        if (tid == 0) {
            float sum = 0.0f;
            int   cnt = 0;
            for (int b = 0; b < B_; ++b) {
                float t = __hip_atomic_load(&totf[b], __ATOMIC_RELAXED,
                                            __HIP_MEMORY_SCOPE_AGENT);
                float l = __hip_atomic_load(&lp[b], __ATOMIC_RELAXED,
                                            __HIP_MEMORY_SCOPE_AGENT);
                float smv = t + 1e-8f;
                if (smv > 1e-8f) { sum += l; cnt += 1; }
            }
            out[0] = cnt > 0 ? sum / fmaxf((float)cnt, 1.0f) : 0.0f;
        }
        return;
    }

    __shared__ float  sA[NBINS];
    __shared__ float  sB[NBINS];
    __shared__ float  sPQ[NBINS][2];
    __shared__ float  sT0[NBINS];
    __shared__ float  sT2[NBINS];
    __shared__ int    s_int[256];
    __shared__ unsigned long long s_pack[256];
    __shared__ double sD0[256];
    __shared__ double sD1[256];
    __shared__ double s_res[4];
    __shared__ int    s_am;

    const int b   = blockIdx.x;
    const float s = 1e-8f;

    int h = hist[b * NBINS + tid];
    s_int[tid] = h;
    __syncthreads();
    for (int off = 128; off > 0; off >>= 1) {
        if (tid < off) s_int[tid] += s_int[tid + off];
        __syncthreads();
    }
    const float ftot = (float)s_int[0];
    __syncthreads();

    float p = (float)h / ftot;
    sPQ[tid][0] = p;
    sPQ[tid][1] = p * (float)tid;
    __syncthreads();

    if (tid == 0) {
        float ch = 0.0f, cm = 0.0f;
#pragma unroll 8
        for (int i = 0; i < NBINS; ++i) {
            ch += sPQ[i][0]; cm += sPQ[i][1];
            sA[i] = ch; sB[i] = cm;
        }
    }
    __syncthreads();

    const float tm = sB[NBINS - 1];
    if (tid < NT) {
        float cb = sA[tid];
        float w2 = 1.0f - cb;
        float mean2 = (tm - sB[tid]) / (w2 + s);
        float d2 = mean2 - tm;
        sT2[tid] = w2 * (d2 * d2);
        float w0 = sA[tid];
        float mean0 = sB[tid] / (w0 + s);
        float d0 = mean0 - tm;
        sT0[tid] = w0 * (d0 * d0);
    }
    __syncthreads();

    unsigned long long best = 0ull;
    if (tid < NT) {
        const float cb  = sA[tid];
        const float m1v = sB[tid];
        const float w2  = 1.0f - cb;
        const float t2v = sT2[tid];
#pragma unroll 4
        for (int i = 0; i < NT; ++i) {
            float w0 = sA[i];
            float w1 = cb - w0;
            float mean1 = (m1v - sB[i]) / (w1 + s);
            float d1 = mean1 - tm;
            float bv = (sT0[i] + w1 * (d1 * d1)) + t2v;
            bool ok = (w0 > 0.f) && (w1 > 0.f) && (w2 > 0.f);
            bv = ok ? bv : 0.0f;
            unsigned k = (unsigned)(i * NT + tid);
            unsigned long long pk =
                ((unsigned long long)__float_as_uint(bv) << 32) | (0xFFFFFFFFu - k);
            best = pk > best ? pk : best;
        }
    }
    s_pack[tid] = best;
    __syncthreads();
    for (int off = 128; off > 0; off >>= 1) {
        if (tid < off) {
            unsigned long long o = s_pack[tid + off];
            if (o > s_pack[tid]) s_pack[tid] = o;
        }
        __syncthreads();
    }
    if (tid == 0)
        s_am = (int)(0xFFFFFFFFu - (unsigned)(s_pack[0] & 0xFFFFFFFFull));
    __syncthreads();

    const int v  = s_am / NT + 1;
    const int wq = s_am % NT + 1;

    int   gc = g0[b * NBINS + tid];
    float gg = g1[b * NBINS + tid];

    sD0[tid] = (tid >= v) ? (double)gc : 0.0;
    sD1[tid] = (tid >= v) ? (double)gg : 0.0;
    __syncthreads();
    for (int off = 128; off > 0; off >>= 1) {
        if (tid < off) { sD0[tid] += sD0[tid + off]; sD1[tid] += sD1[tid + off]; }
        __syncthreads();
    }
    if (tid == 0) { s_res[0] = sD0[0]; s_res[1] = sD1[0]; }
    __syncthreads();

    sD0[tid] = (tid >= wq) ? (double)gc : 0.0;
    sD1[tid] = (tid >= wq) ? (double)gg : 0.0;
    __syncthreads();
    for (int off = 128; off > 0; off >>= 1) {
        if (tid < off) { sD0[tid] += sD0[tid + off]; sD1[tid] += sD1[tid + off]; }
        __syncthreads();
    }

    if (tid == 0) {
        double S0v = s_res[0], S1v = s_res[1];
        double S0w = sD0[0],   S1w = sD1[0];
        double c05 = (v <= wq) ? (S0v - S0w) : 0.0;
        double s05 = (v <= wq) ? (S1v - S1w) : 0.0;
        double sqd = S0w - 2.0 * S1w + 0.25 * c05 - s05 + (double)p2[b];
        float smv = ftot + 1e-8f;
        float lpv = (smv > 1e-8f) ? (float)sqd / smv : 0.0f;
        __hip_atomic_store(&lp[b], lpv, __ATOMIC_RELAXED, __HIP_MEMORY_SCOPE_AGENT);
        __hip_atomic_store(&totf[b], ftot, __ATOMIC_RELAXED, __HIP_MEMORY_SCOPE_AGENT);
        __hip_atomic_store(&flags[b], MAGIC, __ATOMIC_RELEASE, __HIP_MEMORY_SCOPE_AGENT);
    }
}

extern "C" void kernel_launch(void* const* d_in, const int* in_sizes, int n_in,
                              void* d_out, int out_size, void* d_ws, size_t ws_size,
                              hipStream_t stream) {
    const float* preds  = (const float*)d_in[0];
    const float* labels = (const float*)d_in[1];
    const float* images = (const float*)d_in[2];
    float* out = (float*)d_out;
    char* ws = (char*)d_ws;

    if (ws_size >= (size_t)WS_BIG) {
        int*                hist_p   = (int*)ws;
        int*                g0_p     = (int*)(ws + 2097152);
        float*              g1_p     = (float*)(ws + 4194304);
        float*              p2_p     = (float*)(ws + 6291456);
        unsigned long long* packed_s = (unsigned long long*)(ws + 6299648);
        int*                sflag    = (int*)(ws + 6301696);
        float*              lp       = (float*)(ws + 6302720);
        float*              totf     = (float*)(ws + 6302848);
        int*                flags    = (int*)(ws + 6302976);

        k_main_p<<<dim3(64, B_), 256, 0, stream>>>(labels, images, preds,
                                                   hist_p, g0_p, g1_p, p2_p);
        k_search_p<<<257, 256, 0, stream>>>(hist_p, g0_p, g1_p, p2_p,
                                            packed_s, sflag, lp, totf, flags, out);
    } else {
        int*   hist  = (int*)ws;
        int*   g0    = (int*)(ws + 32768);
        float* g1    = (float*)(ws + 65536);
        float* p2    = (float*)(ws + 98304);
        int*   flags = (int*)(ws + 98432);
        float* lp    = (float*)(ws + 98560);
        float* totf  = (float*)(ws + 98688);

        hipMemsetAsync(ws, 0, WS_ZERO, stream);
        k_main_fb<<<dim3(64, B_), 256, 0, stream>>>(labels, images, preds,
                                                    hist, g0, g1, p2);
        k_search_fb<<<33, 256, 0, stream>>>(hist, g0, g1, p2, flags, lp, totf, out);
    }
}